// Round 1
// baseline (1891.424 us; speedup 1.0000x reference)
//
#include <hip/hip_runtime.h>
#include <math.h>

#define NB 256      // batch
#define ND 1024     // d_model
#define NDG 4096    // dg dim
#define NM 65536    // memory size
#define SPARSEK 81  // top-k sparsity
#define NTOPK 32    // recall k
#define EPSF 1e-8f
#define T3 44       // per-half register list capacity (2 threads per batch row)

// ---------------- K1: expanded = relu(q @ W^T + bias), fp32 tiled ----------------
__global__ __launch_bounds__(256) void hm_k1_gemm(
    const float* __restrict__ q, const float* __restrict__ W,
    const float* __restrict__ bias, float* __restrict__ out)
{
    __shared__ float As[16][68];
    __shared__ float Bs[16][68];
    const int t = threadIdx.x;
    const int tx = t & 15, ty = t >> 4;
    const int b0 = (blockIdx.x & 3) * 64;
    const int j0 = (blockIdx.x >> 2) * 64;
    const int lrow = t >> 2;          // 0..63
    const int lk4 = (t & 3) << 2;     // 0,4,8,12

    float acc[4][4];
#pragma unroll
    for (int i = 0; i < 4; ++i)
#pragma unroll
        for (int j = 0; j < 4; ++j) acc[i][j] = 0.f;

    for (int k0 = 0; k0 < ND; k0 += 16) {
        float4 av = *(const float4*)(q + (size_t)(b0 + lrow) * ND + k0 + lk4);
        float4 bv = *(const float4*)(W + (size_t)(j0 + lrow) * ND + k0 + lk4);
        __syncthreads();
        As[lk4 + 0][lrow] = av.x; As[lk4 + 1][lrow] = av.y;
        As[lk4 + 2][lrow] = av.z; As[lk4 + 3][lrow] = av.w;
        Bs[lk4 + 0][lrow] = bv.x; Bs[lk4 + 1][lrow] = bv.y;
        Bs[lk4 + 2][lrow] = bv.z; Bs[lk4 + 3][lrow] = bv.w;
        __syncthreads();
#pragma unroll
        for (int k = 0; k < 16; ++k) {
            float4 a4 = *(const float4*)&As[k][ty << 2];
            float4 b4 = *(const float4*)&Bs[k][tx << 2];
            float aa[4] = {a4.x, a4.y, a4.z, a4.w};
            float bb[4] = {b4.x, b4.y, b4.z, b4.w};
#pragma unroll
            for (int i = 0; i < 4; ++i)
#pragma unroll
                for (int j = 0; j < 4; ++j)
                    acc[i][j] = fmaf(aa[i], bb[j], acc[i][j]);
        }
    }
#pragma unroll
    for (int i = 0; i < 4; ++i) {
        const int row = b0 + (ty << 2) + i;
        const int col = j0 + (tx << 2);
        float4 r;
        r.x = fmaxf(acc[i][0] + bias[col + 0], 0.f);
        r.y = fmaxf(acc[i][1] + bias[col + 1], 0.f);
        r.z = fmaxf(acc[i][2] + bias[col + 2], 0.f);
        r.w = fmaxf(acc[i][3] + bias[col + 3], 0.f);
        *(float4*)(out + (size_t)row * NDG + col) = r;
    }
}

// ---------------- K2: exact 81st-largest radix select + sparse compaction ----------------
// one block per batch row; values are relu outputs (>= 0) so uint bit order == float order
__global__ __launch_bounds__(256) void hm_k2_select(
    const float* __restrict__ expanded,
    float* __restrict__ vals_g, int* __restrict__ idx_g, int* __restrict__ cnt_g)
{
    const int b = blockIdx.x, t = threadIdx.x;
    const float* row = expanded + (size_t)b * NDG;
    float x[16]; unsigned ub[16];
#pragma unroll
    for (int u = 0; u < 16; ++u) { x[u] = row[u * 256 + t]; ub[u] = __float_as_uint(x[u]); }

    __shared__ int hist[256];
    __shared__ unsigned sh_pfx;
    __shared__ int sh_rem;
    unsigned pfx = 0; int rem = SPARSEK;

    for (int pass = 0; pass < 4; ++pass) {
        const int shift = 24 - pass * 8;
        hist[t] = 0;
        __syncthreads();
        const unsigned himask = pass ? (0xFFFFFFFFu << (shift + 8)) : 0u;
#pragma unroll
        for (int u = 0; u < 16; ++u)
            if ((ub[u] & himask) == (pfx & himask))
                atomicAdd(&hist[(ub[u] >> shift) & 255], 1);
        __syncthreads();
        if (t == 0) {
            int cum = 0;
            for (int d = 255; d >= 0; --d) {
                cum += hist[d];
                if (cum >= rem) {
                    sh_pfx = pfx | ((unsigned)d << shift);
                    sh_rem = rem - (cum - hist[d]);
                    break;
                }
            }
        }
        __syncthreads();
        pfx = sh_pfx; rem = sh_rem;
        __syncthreads();
    }
    const float thr = __uint_as_float(pfx);   // exact 81st largest

    __shared__ float sv[128]; __shared__ int sj[128]; __shared__ int scnt;
    __shared__ float red[256];
    if (t == 0) scnt = 0;
    __syncthreads();
    float ssq = 0.f;
#pragma unroll
    for (int u = 0; u < 16; ++u) {
        if (x[u] >= thr) {
            int p = atomicAdd(&scnt, 1);
            if (p < 128) { sv[p] = x[u]; sj[p] = u * 256 + t; }
            ssq += x[u] * x[u];
        }
    }
    red[t] = ssq;
    __syncthreads();
    for (int s = 128; s > 0; s >>= 1) {
        if (t < s) red[t] += red[t + s];
        __syncthreads();
    }
    const float qn = fmaxf(sqrtf(red[0]), EPSF);
    const float inv = 1.f / qn;
    const int cnt = min(scnt, 128);
    if (t < cnt) {
        vals_g[t * NB + b] = sv[t] * inv;   // pre-divide by qn
        idx_g[t * NB + b] = sj[t];
    }
    if (t == 0) cnt_g[b] = cnt;
}

// ---------------- K0: copy usage_counts to output ----------------
__global__ __launch_bounds__(256) void hm_k0_copy(const float* __restrict__ u, float* __restrict__ o)
{
    const int i = blockIdx.x * 256 + threadIdx.x;
    o[i] = u[i];
}

// ---------------- K3: streaming sparse sims + per-thread online top-32 ----------------
// 256 blocks x 512 threads. Block streams 256 key rows (double-buffered LDS).
// Thread t: b = t&255, half = t>>8. Sparse list (44 terms) lives in REGISTERS.
__global__ __launch_bounds__(512) void hm_k3_sims(
    const float* __restrict__ keys, const float* __restrict__ imp,
    const float* __restrict__ vals_g, const int* __restrict__ idx_g,
    const int* __restrict__ cnt_g,
    float* __restrict__ cand_val, int* __restrict__ cand_idx)
{
    __shared__ float kbuf[2][NDG];
    __shared__ float spar[2][NB];
    __shared__ float sssq[2][8];
    const int t = threadIdx.x;
    const int b = t & 255;
    const int half = t >> 8;
    const int wave = t >> 6, lane = t & 63;
    const int m0 = blockIdx.x * 256;

    int cnt = cnt_g[b]; cnt = min(cnt, 128);
    const int h = (cnt + 1) >> 1;
    const int base = half ? h : 0;
    int myn = half ? (cnt - h) : h;
    myn = min(myn, T3);

    float lv[T3]; int li[T3];
#pragma unroll
    for (int i = 0; i < T3; ++i) {
        if (i < myn) { lv[i] = vals_g[(base + i) * NB + b]; li[i] = idx_g[(base + i) * NB + b]; }
        else { lv[i] = 0.f; li[i] = 0; }
    }

    float tkv[NTOPK]; int tki[NTOPK];
#pragma unroll
    for (int k = 0; k < NTOPK; ++k) { tkv[k] = -INFINITY; tki[k] = 0; }
    float tmin = -INFINITY; int tms = 0;

    // stage row 0 into buffer 0
    {
        const float* kr = keys + (size_t)m0 * NDG;
        float4 a = *(const float4*)(kr + t * 8);
        float4 c = *(const float4*)(kr + t * 8 + 4);
        float ss = a.x*a.x + a.y*a.y + a.z*a.z + a.w*a.w
                 + c.x*c.x + c.y*c.y + c.z*c.z + c.w*c.w;
#pragma unroll
        for (int off = 32; off >= 1; off >>= 1) ss += __shfl_xor(ss, off);
        *(float4*)&kbuf[0][t * 8] = a;
        *(float4*)&kbuf[0][t * 8 + 4] = c;
        if (lane == 0) sssq[0][wave] = ss;
    }
    __syncthreads();

    for (int r = 0; r < 256; ++r) {
        const int p = r & 1;
        const int rn = (r < 255) ? (r + 1) : r;
        const float* kr = keys + (size_t)(m0 + rn) * NDG;
        float4 na = *(const float4*)(kr + t * 8);      // prefetch next row
        float4 nc = *(const float4*)(kr + t * 8 + 4);

        // sparse dot over current row
        float acc = 0.f;
#pragma unroll
        for (int i = 0; i < T3; ++i) acc += lv[i] * kbuf[p][li[i]];

        float factor = 0.f;
        if (!half) {
            // kn for row r (partials written when row r was staged; ordered by prior barrier)
            float tot = sssq[p][0] + sssq[p][1] + sssq[p][2] + sssq[p][3]
                      + sssq[p][4] + sssq[p][5] + sssq[p][6] + sssq[p][7];
            float kn = fmaxf(sqrtf(tot), EPSF);
            factor = imp[m0 + r] / kn;
        } else {
            spar[p][b] = acc;   // upper half publishes its partial
        }

        // stage next row into the other buffer
        float ss = na.x*na.x + na.y*na.y + na.z*na.z + na.w*na.w
                 + nc.x*nc.x + nc.y*nc.y + nc.z*nc.z + nc.w*nc.w;
#pragma unroll
        for (int off = 32; off >= 1; off >>= 1) ss += __shfl_xor(ss, off);
        *(float4*)&kbuf[p ^ 1][t * 8] = na;
        *(float4*)&kbuf[p ^ 1][t * 8 + 4] = nc;
        if (lane == 0) sssq[p ^ 1][wave] = ss;
        __syncthreads();

        if (!half) {
            float sim = (acc + spar[p][b]) * factor;
            if (sim > tmin) {                  // strict > keeps earlier m on ties (jax semantics)
#pragma unroll
                for (int k = 0; k < NTOPK; ++k)
                    if (k == tms) { tkv[k] = sim; tki[k] = m0 + r; }
                tmin = tkv[0]; tms = 0;
#pragma unroll
                for (int k = 1; k < NTOPK; ++k)
                    if (tkv[k] < tmin) { tmin = tkv[k]; tms = k; }
            }
        }
    }

    if (!half) {
        const size_t o = ((size_t)blockIdx.x * NB + b) * NTOPK;
#pragma unroll
        for (int k = 0; k < NTOPK; ++k) { cand_val[o + k] = tkv[k]; cand_idx[o + k] = tki[k]; }
    }
}

// ---------------- K4: merge 256x32 candidates -> exact top-32, usage scatter ----------------
__global__ __launch_bounds__(256) void hm_k4_merge(
    const float* __restrict__ cand_val, const int* __restrict__ cand_idx,
    float* __restrict__ top_sim, float* __restrict__ usage_out,
    int* __restrict__ top_idx_g)
{
    const int b = blockIdx.x, t = threadIdx.x;
    float v[32]; int ix[32];
    const size_t o = ((size_t)t * NB + b) * NTOPK;   // thread t owns source block t
#pragma unroll
    for (int k = 0; k < 32; ++k) { v[k] = cand_val[o + k]; ix[k] = cand_idx[o + k]; }

    __shared__ float wv[4]; __shared__ int wi[4];
    __shared__ float sbv;   __shared__ int sbi;
    const int lane = t & 63, wave = t >> 6;

    for (int it = 0; it < NTOPK; ++it) {
        float bv = -INFINITY; int bi = 0x7FFFFFFF;
#pragma unroll
        for (int k = 0; k < 32; ++k)
            if (v[k] > bv || (v[k] == bv && ix[k] < bi)) { bv = v[k]; bi = ix[k]; }
#pragma unroll
        for (int off = 1; off < 64; off <<= 1) {
            float ov = __shfl_xor(bv, off);
            int   oi = __shfl_xor(bi, off);
            if (ov > bv || (ov == bv && oi < bi)) { bv = ov; bi = oi; }
        }
        if (lane == 0) { wv[wave] = bv; wi[wave] = bi; }
        __syncthreads();
        if (t == 0) {
            float fv = wv[0]; int fi = wi[0];
#pragma unroll
            for (int w = 1; w < 4; ++w)
                if (wv[w] > fv || (wv[w] == fv && wi[w] < fi)) { fv = wv[w]; fi = wi[w]; }
            sbv = fv; sbi = fi;
            top_sim[b * NTOPK + it] = fv;
            top_idx_g[b * NTOPK + it] = fi;
            atomicAdd(&usage_out[fi], 1.0f);
        }
        __syncthreads();
        const float fv = sbv; const int fi = sbi;
#pragma unroll
        for (int k = 0; k < 32; ++k)
            if (ix[k] == fi && v[k] == fv) v[k] = -INFINITY;   // remove winner
        __syncthreads();
    }
}

// ---------------- K5: gather retrieved rows ----------------
__global__ __launch_bounds__(256) void hm_k5_gather(
    const float* __restrict__ values, const int* __restrict__ top_idx_g,
    float* __restrict__ out)
{
    const int blk = blockIdx.x;                 // 8192 = 256*32
    const int idx = top_idx_g[blk];
    const float4* src = (const float4*)(values + (size_t)idx * ND);
    float4* dst = (float4*)(out + (size_t)blk * ND);
    dst[threadIdx.x] = src[threadIdx.x];
}

extern "C" void kernel_launch(void* const* d_in, const int* in_sizes, int n_in,
                              void* d_out, int out_size, void* d_ws, size_t ws_size,
                              hipStream_t stream) {
    const float* q     = (const float*)d_in[0];
    const float* W     = (const float*)d_in[1];
    const float* bias  = (const float*)d_in[2];
    const float* keys  = (const float*)d_in[3];
    const float* vals  = (const float*)d_in[4];
    const float* imp   = (const float*)d_in[5];
    const float* usage = (const float*)d_in[6];
    // d_in[7] = k (always 32, hardcoded)

    char* ws = (char*)d_ws;
    float* expanded = (float*)(ws);                       // 4,194,304 B
    float* vals_g   = (float*)(ws + 4194304);             // 131,072 B
    int*   idx_g    = (int*)  (ws + 4325376);             // 131,072 B
    int*   cnt_g    = (int*)  (ws + 4456448);             // 1,024 B
    float* cand_val = (float*)(ws + 4457472);             // 8,388,608 B
    int*   cand_idx = (int*)  (ws + 12846080);            // 8,388,608 B
    int*   tidx     = (int*)  (ws + 21234688);            // 32,768 B

    float* out       = (float*)d_out;
    float* out_ret   = out;                 // 256*32*1024
    float* out_sim   = out + 8388608;       // 256*32
    float* out_usage = out + 8396800;       // 65536

    hm_k1_gemm  <<<256, 256, 0, stream>>>(q, W, bias, expanded);
    hm_k2_select<<<256, 256, 0, stream>>>(expanded, vals_g, idx_g, cnt_g);
    hm_k0_copy  <<<256, 256, 0, stream>>>(usage, out_usage);
    hm_k3_sims  <<<256, 512, 0, stream>>>(keys, imp, vals_g, idx_g, cnt_g, cand_val, cand_idx);
    hm_k4_merge <<<256, 256, 0, stream>>>(cand_val, cand_idx, out_sim, out_usage, tidx);
    hm_k5_gather<<<8192, 256, 0, stream>>>(vals, tidx, out_ret);
}